// Round 2
// baseline (912.292 us; speedup 1.0000x reference)
//
#include <hip/hip_runtime.h>
#include <stdint.h>

#define T_STEPS 100
#define D_IN 16
#define H_DIM 32
#define HD 50
#define KXH 48
#define EULER 10
#define STEPF 0.1f
#define DT_SCALERF (1.0f/24.0f)
#define TANH_SCALE 2.8853900817779268f   // 2*log2(e), folded into W1/W2/W3(+biases)

typedef __attribute__((ext_vector_type(8))) short short8;
typedef __attribute__((ext_vector_type(4))) float float4v;
typedef __attribute__((ext_vector_type(4))) uint32_t uint4v;

// input pre-scaled by 2*log2(e): tanh(u) = 1 - 2/(exp2(us)+1)
__device__ __forceinline__ float tanh_pre(float us) {
    float e = __builtin_amdgcn_exp2f(us);
    return 1.0f - 2.0f * __builtin_amdgcn_rcpf(e + 1.0f);
}
// single-instruction bf16 pair pack (RNE), lo -> bits[15:0], hi -> bits[31:16]
__device__ __forceinline__ uint32_t pkbf(float lo, float hi) {
    uint32_t r;
    asm("v_cvt_pk_bf16_f32 %0, %1, %2" : "=v"(r) : "v"(lo), "v"(hi));
    return r;
}
// init-time scalar RNE bf16 (weights only)
__device__ __forceinline__ short f2bf(float f) {
    uint32_t u = __builtin_bit_cast(uint32_t, f);
    u = u + 0x7fffu + ((u >> 16) & 1u);
    return (short)(u >> 16);
}

// z-slot kk (0..63) -> original u1 feature (0..49), or -1 if pad.
//   kk = 32*(t>>1) + 8*q + 4*(t&1) + r   (u1 C-layout == u2 B-frag layout, same lane)
__device__ __forceinline__ int zorig(int kk) {
    int f = kk >> 5, q = (kk >> 3) & 3, jj = kk & 7;
    int t = 2 * f + (jj >> 2), r = jj & 3;
    if (t < 3) return t * 16 + q * 4 + r;
    if (r == 0 && q < 2) return 48 + q;
    return -1;
}

// 2-wave block, 32 batches/block = TWO independent 16-batch groups per wave (ILP-2).
// Wave 0 (critical): u1 -> z -> u2 -> h for groups A,B interleaved, all in registers;
//   weight frags shared across groups. Wave 1 (slack): u3 -> dy -> y for A,B, h via
//   2-slot LDS ring one step behind. One raw s_barrier per Euler step (lgkmcnt-only
//   drain: prefetch vmcnt stays in flight across barriers).
__global__ __launch_bounds__(128, 1) void latode_kernel(
    const float* __restrict__ dt, const float* __restrict__ x,
    const float* __restrict__ W1, const float* __restrict__ b1,
    const float* __restrict__ W2, const float* __restrict__ b2,
    const float* __restrict__ W3, const float* __restrict__ b3,
    const float* __restrict__ W4, const float* __restrict__ b4,
    float* __restrict__ out)
{
    const int tid  = threadIdx.x;
    const int wave = tid >> 6;
    const int lane = tid & 63;
    const int n16  = lane & 15;       // batch column within group
    const int quad = lane >> 4;
    const int b0   = blockIdx.x * 32;

    __shared__ __align__(16) uint32_t hslot[2][2][256];   // [ring][group][lane*4]

    // zero ring (h_0 = 0); LDS is poisoned 0xAA pre-launch
    for (int i = tid; i < 1024; i += 128) ((uint32_t*)hslot)[i] = 0;

    const float* xr0 = x + (size_t)(b0 + n16) * (T_STEPS * D_IN);
    const float* dr0 = dt + (size_t)(b0 + n16) * (T_STEPS * 2);
    const float* xrow[2] = { xr0, xr0 + 16 * T_STEPS * D_IN };
    const float* drow[2] = { dr0, dr0 + 16 * T_STEPS * 2 };

    // ---------------- weight fragments (shared across groups) ----------------
    short8 w1h[4], w1x[4], w2f[2][2];   // wave 0
    short8 w3f[4];                      // wave 1
    float4v b3v[4], w4v4[4];            // wave 1

    if (wave == 0) {
        // u1: A-frag feature m=n16 of tile t lands at C(q=m>>2, r=m&3) -> z-slot kz
#pragma unroll
        for (int t = 0; t < 4; ++t) {
            int kz = 32 * (t >> 1) + 8 * (n16 >> 2) + 4 * (t & 1) + (n16 & 3);
            int of = zorig(kz);                      // original W1 row, or pad
#pragma unroll
            for (int j = 0; j < 8; ++j) {
                int kk = quad * 8 + j;
                float wh = 0.0f, wx = 0.0f;
                if (of >= 0) {
                    wh = W1[of * KXH + 16 + kk];     // h columns
                    if (kk < 16)       wx = W1[of * KXH + kk];   // x columns
                    else if (kk == 16) wx = b1[of];              // bias via const-1.0 slot
                }
                w1h[t][j] = f2bf(wh * TANH_SCALE);
                w1x[t][j] = f2bf(wx * TANH_SCALE);
            }
        }
        // u2: rows permuted so output lands in h B-frag order; cols in z-slot order
#pragma unroll
        for (int t2 = 0; t2 < 2; ++t2) {
            int hrow = 8 * (n16 >> 2) + 4 * t2 + (n16 & 3);
#pragma unroll
            for (int kt = 0; kt < 2; ++kt)
#pragma unroll
            for (int j = 0; j < 8; ++j) {
                int kk = kt * 32 + quad * 8 + j;
                int oz = zorig(kk);
                float w = 0.0f;
                if (oz >= 0)       w = W2[hrow * HD + oz];
                else if (kk == 63) w = b2[hrow];
                w2f[t2][kt][j] = f2bf(w * TANH_SCALE);
            }
        }
    } else {
        // u3/W4: natural layout (dy is an order-agnostic reduction)
#pragma unroll
        for (int t = 0; t < 4; ++t) {
            int f = t * 16 + n16;
#pragma unroll
            for (int j = 0; j < 8; ++j)
                w3f[t][j] = f2bf(W3[f * H_DIM + quad * 8 + j] * TANH_SCALE);
#pragma unroll
            for (int r = 0; r < 4; ++r) {
                int fr = t * 16 + quad * 4 + r;
                b3v[t][r]  = b3[fr] * TANH_SCALE;
                w4v4[t][r] = W4[fr];
            }
        }
    }
    const float b4s = b4[0];

    // ---------------- per-group state ----------------
    const float4v zero4 = {0.f,0.f,0.f,0.f};
    float4v hC0[2], hC1[2];
    short8  hB[2];
#pragma unroll
    for (int g = 0; g < 2; ++g) {
        hC0[g] = zero4; hC1[g] = zero4;
        hB[g] = (short8){0,0,0,0,0,0,0,0};
    }
    const uint32_t z1d3 = (quad == 3) ? 0x3f800000u : 0u;   // z-slot 63 = 1.0 (b2 carrier)

    // t=0 prefetch
    float4 xa[2] = {{0,0,0,0},{0,0,0,0}}, xb[2] = {{0,0,0,0},{0,0,0,0}};
    float2 dtv[2] = {{0.f,0.f},{0.f,0.f}};
    float y0[2] = {0.f, 0.f};
    if (wave == 0) {
#pragma unroll
        for (int g = 0; g < 2; ++g) {
            if (quad < 2) {
                xa[g] = *(const float4*)(xrow[g] + quad * 8);
                xb[g] = *(const float4*)(xrow[g] + quad * 8 + 4);
            }
            dtv[g] = *(const float2*)drow[g];
        }
    } else {
#pragma unroll
        for (int g = 0; g < 2; ++g) {
            dtv[g] = *(const float2*)drow[g];
            y0[g]  = xrow[g][0];
        }
    }

    __syncthreads();   // ring zero visible

#pragma unroll 1
    for (int t = 0; t < T_STEPS; ++t) {
        float s10[2], y0c[2], psum[2];
#pragma unroll
        for (int g = 0; g < 2; ++g) {
            s10[g]  = (dtv[g].y - dtv[g].x) * (DT_SCALERF * STEPF);
            y0c[g]  = y0[g];
            psum[g] = 0.f;
        }

        float4v cxa[2][4];
        if (wave == 0) {
            // per-t x contribution + bias: cx = W1x . [x | 1]
#pragma unroll
            for (int g = 0; g < 2; ++g) {
                uint4v xp = {0,0,0,0};
                if (quad < 2) {
                    xp[0] = pkbf(xa[g].x, xa[g].y); xp[1] = pkbf(xa[g].z, xa[g].w);
                    xp[2] = pkbf(xb[g].x, xb[g].y); xp[3] = pkbf(xb[g].z, xb[g].w);
                } else if (quad == 2) {
                    xp[0] = 0x00003f80u;      // bf16(1.0) -> x-slot 16
                }
                short8 xB = __builtin_bit_cast(short8, xp);
#pragma unroll
                for (int tt = 0; tt < 4; ++tt)
                    cxa[g][tt] = __builtin_amdgcn_mfma_f32_16x16x32_bf16(w1x[tt], xB, zero4, 0, 0, 0);
            }
        }

        { // prefetch t+1 (stays in flight across the raw barriers below)
            int tn = (t + 1 < T_STEPS) ? t + 1 : (T_STEPS - 1);
            if (wave == 0) {
#pragma unroll
                for (int g = 0; g < 2; ++g) {
                    if (quad < 2) {
                        xa[g] = *(const float4*)(xrow[g] + tn * D_IN + quad * 8);
                        xb[g] = *(const float4*)(xrow[g] + tn * D_IN + quad * 8 + 4);
                    }
                    dtv[g] = *(const float2*)(drow[g] + tn * 2);
                }
            } else {
#pragma unroll
                for (int g = 0; g < 2; ++g) {
                    dtv[g] = *(const float2*)(drow[g] + tn * 2);
                    y0[g]  = xrow[g][tn * D_IN];
                }
            }
        }

#pragma unroll 2
        for (int e = 0; e < EULER; ++e) {
            if (wave == 0) {
#pragma unroll
                for (int g = 0; g < 2; ++g) {
                    // ---- u1 (K = h only; x+bias pre-folded in cxa) ----
                    float4v a0 = __builtin_amdgcn_mfma_f32_16x16x32_bf16(w1h[0], hB[g], cxa[g][0], 0, 0, 0);
                    float4v a1 = __builtin_amdgcn_mfma_f32_16x16x32_bf16(w1h[1], hB[g], cxa[g][1], 0, 0, 0);
                    float4v a2 = __builtin_amdgcn_mfma_f32_16x16x32_bf16(w1h[2], hB[g], cxa[g][2], 0, 0, 0);
                    float4v a3 = __builtin_amdgcn_mfma_f32_16x16x32_bf16(w1h[3], hB[g], cxa[g][3], 0, 0, 0);
                    // ---- tanh + pack (C-layout == next B-frag layout, same lane) ----
                    uint4v z0, z1;
                    z0[0] = pkbf(tanh_pre(a0[0]), tanh_pre(a0[1]));
                    z0[1] = pkbf(tanh_pre(a0[2]), tanh_pre(a0[3]));
                    z0[2] = pkbf(tanh_pre(a1[0]), tanh_pre(a1[1]));
                    z0[3] = pkbf(tanh_pre(a1[2]), tanh_pre(a1[3]));
                    z1[0] = pkbf(tanh_pre(a2[0]), tanh_pre(a2[1]));
                    z1[1] = pkbf(tanh_pre(a2[2]), tanh_pre(a2[3]));
                    z1[2] = pkbf(tanh_pre(a3[0]), 0.0f);   // feats 48,49; pads self-zero
                    z1[3] = z1d3;                          // b2 carrier slot
                    short8 zf0 = __builtin_bit_cast(short8, z0);
                    short8 zf1 = __builtin_bit_cast(short8, z1);
                    // ---- u2 ----
                    float4v u20 = __builtin_amdgcn_mfma_f32_16x16x32_bf16(w2f[0][0], zf0, zero4, 0, 0, 0);
                    u20 = __builtin_amdgcn_mfma_f32_16x16x32_bf16(w2f[0][1], zf1, u20, 0, 0, 0);
                    float4v u21 = __builtin_amdgcn_mfma_f32_16x16x32_bf16(w2f[1][0], zf0, zero4, 0, 0, 0);
                    u21 = __builtin_amdgcn_mfma_f32_16x16x32_bf16(w2f[1][1], zf1, u21, 0, 0, 0);
                    // ---- h update (fp32 master) + repack ----
                    hC0[g][0] += s10[g] * tanh_pre(u20[0]);
                    hC0[g][1] += s10[g] * tanh_pre(u20[1]);
                    hC0[g][2] += s10[g] * tanh_pre(u20[2]);
                    hC0[g][3] += s10[g] * tanh_pre(u20[3]);
                    hC1[g][0] += s10[g] * tanh_pre(u21[0]);
                    hC1[g][1] += s10[g] * tanh_pre(u21[1]);
                    hC1[g][2] += s10[g] * tanh_pre(u21[2]);
                    hC1[g][3] += s10[g] * tanh_pre(u21[3]);
                    uint4v hp;
                    hp[0] = pkbf(hC0[g][0], hC0[g][1]); hp[1] = pkbf(hC0[g][2], hC0[g][3]);
                    hp[2] = pkbf(hC1[g][0], hC1[g][1]); hp[3] = pkbf(hC1[g][2], hC1[g][3]);
                    hB[g] = __builtin_bit_cast(short8, hp);
                    *(uint4v*)&hslot[(e + 1) & 1][g][lane * 4] = hp;   // publish for wave 1
                }
            } else {
#pragma unroll
                for (int g = 0; g < 2; ++g) {
                    // ---- u3 / dy on h_e (one step behind producer) ----
                    short8 hb = __builtin_bit_cast(short8, *(const uint4v*)&hslot[e & 1][g][lane * 4]);
                    float4v a0 = __builtin_amdgcn_mfma_f32_16x16x32_bf16(w3f[0], hb, b3v[0], 0, 0, 0);
                    float4v a1 = __builtin_amdgcn_mfma_f32_16x16x32_bf16(w3f[1], hb, b3v[1], 0, 0, 0);
                    float4v a2 = __builtin_amdgcn_mfma_f32_16x16x32_bf16(w3f[2], hb, b3v[2], 0, 0, 0);
                    float4v a3 = __builtin_amdgcn_mfma_f32_16x16x32_bf16(w3f[3], hb, b3v[3], 0, 0, 0);
                    float p0 = w4v4[0][0]*tanh_pre(a0[0]) + w4v4[0][1]*tanh_pre(a0[1])
                             + w4v4[0][2]*tanh_pre(a0[2]) + w4v4[0][3]*tanh_pre(a0[3]);
                    float p1 = w4v4[1][0]*tanh_pre(a1[0]) + w4v4[1][1]*tanh_pre(a1[1])
                             + w4v4[1][2]*tanh_pre(a1[2]) + w4v4[1][3]*tanh_pre(a1[3]);
                    float p2 = w4v4[2][0]*tanh_pre(a2[0]) + w4v4[2][1]*tanh_pre(a2[1])
                             + w4v4[2][2]*tanh_pre(a2[2]) + w4v4[2][3]*tanh_pre(a2[3]);
                    float p3 = w4v4[3][0]*tanh_pre(a3[0]) + w4v4[3][1]*tanh_pre(a3[1])
                             + w4v4[3][2]*tanh_pre(a3[2]) + w4v4[3][3]*tanh_pre(a3[3]);
                    psum[g] += (p0 + p1) + (p2 + p3);   // quad-reduce deferred to end of t
                }
            }
            // raw barrier: drain LDS only; prefetch vmcnt stays in flight (T4)
            asm volatile("s_waitcnt lgkmcnt(0)" ::: "memory");
            __builtin_amdgcn_s_barrier();
            __builtin_amdgcn_sched_barrier(0);
        } // euler

        if (wave == 1) {
#pragma unroll
            for (int g = 0; g < 2; ++g) {
                float pacc = psum[g];
                pacc += __shfl_xor(pacc, 16, 64);
                pacc += __shfl_xor(pacc, 32, 64);
                if (lane < 16)
                    out[(size_t)(b0 + g * 16 + n16) * T_STEPS + t] =
                        y0c[g] + s10[g] * (pacc + (float)EULER * b4s);
            }
        }
    } // t
}

extern "C" void kernel_launch(void* const* d_in, const int* in_sizes, int n_in,
                              void* d_out, int out_size, void* d_ws, size_t ws_size,
                              hipStream_t stream) {
    const float* dt = (const float*)d_in[0];
    const float* x  = (const float*)d_in[1];
    const float* W1 = (const float*)d_in[2];
    const float* b1 = (const float*)d_in[3];
    const float* W2 = (const float*)d_in[4];
    const float* b2 = (const float*)d_in[5];
    const float* W3 = (const float*)d_in[6];
    const float* b3 = (const float*)d_in[7];
    const float* W4 = (const float*)d_in[8];
    const float* b4 = (const float*)d_in[9];
    float* out = (float*)d_out;

    const int B = 8192;
    dim3 grid(B / 32), block(128);
    latode_kernel<<<grid, block, 0, stream>>>(dt, x, W1, b1, W2, b2, W3, b3, W4, b4, out);
}

// Round 3
// 690.717 us; speedup vs baseline: 1.3208x; 1.3208x over previous
//
#include <hip/hip_runtime.h>
#include <stdint.h>

#define T_STEPS 100
#define D_IN 16
#define H_DIM 32
#define HD 50
#define KXH 48
#define EULER 10
#define STEPF 0.1f
#define DT_SCALERF (1.0f/24.0f)
#define TANH_SCALE 2.8853900817779268f   // 2*log2(e), folded into W1/W2/W3(+biases)

typedef __attribute__((ext_vector_type(8))) short short8;
typedef __attribute__((ext_vector_type(4))) float float4v;
typedef __attribute__((ext_vector_type(4))) uint32_t uint4v;

// input pre-scaled by 2*log2(e): tanh(u) = 1 - 2/(exp2(us)+1)
__device__ __forceinline__ float tanh_pre(float us) {
    float e = __builtin_amdgcn_exp2f(us);
    return 1.0f - 2.0f * __builtin_amdgcn_rcpf(e + 1.0f);
}
// single-instruction bf16 pair pack (RNE), lo -> bits[15:0], hi -> bits[31:16]
__device__ __forceinline__ uint32_t pkbf(float lo, float hi) {
    uint32_t r;
    asm("v_cvt_pk_bf16_f32 %0, %1, %2" : "=v"(r) : "v"(lo), "v"(hi));
    return r;
}
// init-time scalar RNE bf16 (weights only)
__device__ __forceinline__ short f2bf(float f) {
    uint32_t u = __builtin_bit_cast(uint32_t, f);
    u = u + 0x7fffu + ((u >> 16) & 1u);
    return (short)(u >> 16);
}

// z-slot kk (0..63) -> original u1 feature (0..49), or -1 if pad.
//   kk = 32*(t>>1) + 8*q + 4*(t&1) + r   (u1 C-layout == u2 B-frag layout, same lane)
__device__ __forceinline__ int zorig(int kk) {
    int f = kk >> 5, q = (kk >> 3) & 3, jj = kk & 7;
    int t = 2 * f + (jj >> 2), r = jj & 3;
    if (t < 3) return t * 16 + q * 4 + r;
    if (r == 0 && q < 2) return 48 + q;
    return -1;
}

// ONE wave per 16-batch group; the ENTIRE model step lives in this wave's
// registers. u1->z->u2->h is the serial chain; u3->dy (depends only on
// h at step start) is issued alongside as the stall filler. No LDS, no
// barriers, no cross-wave traffic of any kind.
__global__ __launch_bounds__(64, 1) void latode_kernel(
    const float* __restrict__ dt, const float* __restrict__ x,
    const float* __restrict__ W1, const float* __restrict__ b1,
    const float* __restrict__ W2, const float* __restrict__ b2,
    const float* __restrict__ W3, const float* __restrict__ b3,
    const float* __restrict__ W4, const float* __restrict__ b4,
    float* __restrict__ out)
{
    const int lane = threadIdx.x & 63;
    const int n16  = lane & 15;       // batch column
    const int quad = lane >> 4;
    const int b0   = blockIdx.x * 16;

    const float* xrow = x + (size_t)(b0 + n16) * (T_STEPS * D_IN);
    const float* drow = dt + (size_t)(b0 + n16) * (T_STEPS * 2);

    // ---------------- weight fragments (all owned by this wave) ----------------
    short8 w1h[4], w1x[4], w2f[2][2], w3f[4];
    float4v b3v[4], w4v4[4];

    // u1: A-frag feature m=n16 of tile t lands at C(q=m>>2, r=m&3) -> z-slot kz
#pragma unroll
    for (int t = 0; t < 4; ++t) {
        int kz = 32 * (t >> 1) + 8 * (n16 >> 2) + 4 * (t & 1) + (n16 & 3);
        int of = zorig(kz);                      // original W1 row, or pad
#pragma unroll
        for (int j = 0; j < 8; ++j) {
            int kk = quad * 8 + j;
            float wh = 0.0f, wx = 0.0f;
            if (of >= 0) {
                wh = W1[of * KXH + 16 + kk];     // h columns
                if (kk < 16)       wx = W1[of * KXH + kk];   // x columns
                else if (kk == 16) wx = b1[of];              // bias via const-1.0 slot
            }
            w1h[t][j] = f2bf(wh * TANH_SCALE);
            w1x[t][j] = f2bf(wx * TANH_SCALE);
        }
    }
    // u2: rows permuted so output lands in h B-frag order; cols in z-slot order
#pragma unroll
    for (int t2 = 0; t2 < 2; ++t2) {
        int hrow = 8 * (n16 >> 2) + 4 * t2 + (n16 & 3);
#pragma unroll
        for (int kt = 0; kt < 2; ++kt)
#pragma unroll
        for (int j = 0; j < 8; ++j) {
            int kk = kt * 32 + quad * 8 + j;
            int oz = zorig(kk);
            float w = 0.0f;
            if (oz >= 0)       w = W2[hrow * HD + oz];
            else if (kk == 63) w = b2[hrow];
            w2f[t2][kt][j] = f2bf(w * TANH_SCALE);
        }
    }
    // u3/W4: natural layout (dy is an order-agnostic reduction)
#pragma unroll
    for (int t = 0; t < 4; ++t) {
        int f = t * 16 + n16;
#pragma unroll
        for (int j = 0; j < 8; ++j)
            w3f[t][j] = f2bf(W3[f * H_DIM + quad * 8 + j] * TANH_SCALE);
#pragma unroll
        for (int r = 0; r < 4; ++r) {
            int fr = t * 16 + quad * 4 + r;
            b3v[t][r]  = b3[fr] * TANH_SCALE;
            w4v4[t][r] = W4[fr];
        }
    }
    const float b4s = b4[0];

    // ---------------- state ----------------
    const float4v zero4 = {0.f,0.f,0.f,0.f};
    float4v hC0 = zero4, hC1 = zero4;                       // fp32 h master
    short8  hB  = (short8){0,0,0,0,0,0,0,0};                // bf16 h frag
    const uint32_t z1d3 = (quad == 3) ? 0x3f800000u : 0u;   // z-slot 63 = 1.0 (b2 carrier)

    // t=0 prefetch
    float4 xa = {0,0,0,0}, xb = {0,0,0,0};
    float2 dtv;
    float y0;
    if (quad < 2) {
        xa = *(const float4*)(xrow + quad * 8);
        xb = *(const float4*)(xrow + quad * 8 + 4);
    }
    dtv = *(const float2*)drow;
    y0  = xrow[0];

#pragma unroll 1
    for (int t = 0; t < T_STEPS; ++t) {
        const float s10 = (dtv.y - dtv.x) * (DT_SCALERF * STEPF);
        const float y0c = y0;
        float psum = 0.f;

        // per-t x contribution + bias: cx = W1x . [x | 1]  (const-1.0 at x-slot 16)
        float4v cxa[4];
        {
            uint4v xp = {0,0,0,0};
            if (quad < 2) {
                xp[0] = pkbf(xa.x, xa.y); xp[1] = pkbf(xa.z, xa.w);
                xp[2] = pkbf(xb.x, xb.y); xp[3] = pkbf(xb.z, xb.w);
            } else if (quad == 2) {
                xp[0] = 0x00003f80u;      // bf16(1.0) -> x-slot 16
            }
            short8 xB = __builtin_bit_cast(short8, xp);
#pragma unroll
            for (int tt = 0; tt < 4; ++tt)
                cxa[tt] = __builtin_amdgcn_mfma_f32_16x16x32_bf16(w1x[tt], xB, zero4, 0, 0, 0);
        }

        { // prefetch t+1 (no barriers anywhere: loads drain whenever ready)
            int tn = (t + 1 < T_STEPS) ? t + 1 : (T_STEPS - 1);
            if (quad < 2) {
                xa = *(const float4*)(xrow + tn * D_IN + quad * 8);
                xb = *(const float4*)(xrow + tn * D_IN + quad * 8 + 4);
            }
            dtv = *(const float2*)(drow + tn * 2);
            y0  = xrow[tn * D_IN];
        }

#pragma unroll 2
        for (int e = 0; e < EULER; ++e) {
            // ---- u1 MFMAs (chain head, dep on hB) ----
            float4v a0 = __builtin_amdgcn_mfma_f32_16x16x32_bf16(w1h[0], hB, cxa[0], 0, 0, 0);
            float4v a1 = __builtin_amdgcn_mfma_f32_16x16x32_bf16(w1h[1], hB, cxa[1], 0, 0, 0);
            float4v a2 = __builtin_amdgcn_mfma_f32_16x16x32_bf16(w1h[2], hB, cxa[2], 0, 0, 0);
            float4v a3 = __builtin_amdgcn_mfma_f32_16x16x32_bf16(w1h[3], hB, cxa[3], 0, 0, 0);
            // ---- u3 MFMAs (independent filler, dep on hB only) ----
            float4v c0 = __builtin_amdgcn_mfma_f32_16x16x32_bf16(w3f[0], hB, b3v[0], 0, 0, 0);
            float4v c1 = __builtin_amdgcn_mfma_f32_16x16x32_bf16(w3f[1], hB, b3v[1], 0, 0, 0);
            float4v c2 = __builtin_amdgcn_mfma_f32_16x16x32_bf16(w3f[2], hB, b3v[2], 0, 0, 0);
            float4v c3 = __builtin_amdgcn_mfma_f32_16x16x32_bf16(w3f[3], hB, b3v[3], 0, 0, 0);

            // ---- z = tanh(u1), pack (C-layout == u2 B-frag layout, same lane) ----
            uint4v z0, z1;
            z0[0] = pkbf(tanh_pre(a0[0]), tanh_pre(a0[1]));
            z0[1] = pkbf(tanh_pre(a0[2]), tanh_pre(a0[3]));
            z0[2] = pkbf(tanh_pre(a1[0]), tanh_pre(a1[1]));
            z0[3] = pkbf(tanh_pre(a1[2]), tanh_pre(a1[3]));
            z1[0] = pkbf(tanh_pre(a2[0]), tanh_pre(a2[1]));
            z1[1] = pkbf(tanh_pre(a2[2]), tanh_pre(a2[3]));
            z1[2] = pkbf(tanh_pre(a3[0]), 0.0f);   // feats 48,49; pads self-zero
            z1[3] = z1d3;                          // b2 carrier slot
            short8 zf0 = __builtin_bit_cast(short8, z0);
            short8 zf1 = __builtin_bit_cast(short8, z1);

            // ---- u2 MFMAs ----
            float4v u20 = __builtin_amdgcn_mfma_f32_16x16x32_bf16(w2f[0][0], zf0, zero4, 0, 0, 0);
            u20 = __builtin_amdgcn_mfma_f32_16x16x32_bf16(w2f[0][1], zf1, u20, 0, 0, 0);
            float4v u21 = __builtin_amdgcn_mfma_f32_16x16x32_bf16(w2f[1][0], zf0, zero4, 0, 0, 0);
            u21 = __builtin_amdgcn_mfma_f32_16x16x32_bf16(w2f[1][1], zf1, u21, 0, 0, 0);

            // ---- u3 tanh + dy dot (fills u2 MFMA latency) ----
            float p0 = w4v4[0][0]*tanh_pre(c0[0]) + w4v4[0][1]*tanh_pre(c0[1])
                     + w4v4[0][2]*tanh_pre(c0[2]) + w4v4[0][3]*tanh_pre(c0[3]);
            float p1 = w4v4[1][0]*tanh_pre(c1[0]) + w4v4[1][1]*tanh_pre(c1[1])
                     + w4v4[1][2]*tanh_pre(c1[2]) + w4v4[1][3]*tanh_pre(c1[3]);
            float p2 = w4v4[2][0]*tanh_pre(c2[0]) + w4v4[2][1]*tanh_pre(c2[1])
                     + w4v4[2][2]*tanh_pre(c2[2]) + w4v4[2][3]*tanh_pre(c2[3]);
            float p3 = w4v4[3][0]*tanh_pre(c3[0]) + w4v4[3][1]*tanh_pre(c3[1])
                     + w4v4[3][2]*tanh_pre(c3[2]) + w4v4[3][3]*tanh_pre(c3[3]);
            psum += (p0 + p1) + (p2 + p3);         // quad-reduce deferred to end of t

            // ---- h update (fp32 master) + repack (C-layout == h B-frag) ----
            hC0[0] += s10 * tanh_pre(u20[0]);
            hC0[1] += s10 * tanh_pre(u20[1]);
            hC0[2] += s10 * tanh_pre(u20[2]);
            hC0[3] += s10 * tanh_pre(u20[3]);
            hC1[0] += s10 * tanh_pre(u21[0]);
            hC1[1] += s10 * tanh_pre(u21[1]);
            hC1[2] += s10 * tanh_pre(u21[2]);
            hC1[3] += s10 * tanh_pre(u21[3]);
            uint4v hp;
            hp[0] = pkbf(hC0[0], hC0[1]); hp[1] = pkbf(hC0[2], hC0[3]);
            hp[2] = pkbf(hC1[0], hC1[1]); hp[3] = pkbf(hC1[2], hC1[3]);
            hB = __builtin_bit_cast(short8, hp);
        } // euler

        // y = y0 + s10 * (sum_e dy_e); quad-reduce once per t
        float pacc = psum;
        pacc += __shfl_xor(pacc, 16, 64);
        pacc += __shfl_xor(pacc, 32, 64);
        if (lane < 16)
            out[(size_t)(b0 + n16) * T_STEPS + t] = y0c + s10 * (pacc + (float)EULER * b4s);
    } // t
}

extern "C" void kernel_launch(void* const* d_in, const int* in_sizes, int n_in,
                              void* d_out, int out_size, void* d_ws, size_t ws_size,
                              hipStream_t stream) {
    const float* dt = (const float*)d_in[0];
    const float* x  = (const float*)d_in[1];
    const float* W1 = (const float*)d_in[2];
    const float* b1 = (const float*)d_in[3];
    const float* W2 = (const float*)d_in[4];
    const float* b2 = (const float*)d_in[5];
    const float* W3 = (const float*)d_in[6];
    const float* b3 = (const float*)d_in[7];
    const float* W4 = (const float*)d_in[8];
    const float* b4 = (const float*)d_in[9];
    float* out = (float*)d_out;

    const int B = 8192;
    dim3 grid(B / 16), block(64);
    latode_kernel<<<grid, block, 0, stream>>>(dt, x, W1, b1, W2, b2, W3, b3, W4, b4, out);
}